// Round 13
// baseline (206.569 us; speedup 1.0000x reference)
//
#include <hip/hip_runtime.h>

#define NUM_EMB 1024
#define EMB_DIM 256
#define NPIX    32768      // 32 * 32 * 32
#define HW      1024       // 32*32 spatial per batch
#define ZQ_ELEMS 8388608   // 32*256*32*32

// ws layout (bytes):
//   [0..8)                  double loss_accum
//   [8..8+4096)             float  tnorm[1024]
//   [8192..+131072)         float  snorm[32768]
//   [139264..+262144)       u64    keys[32768]  (argmin: (d_bits<<32)|idx)
//   [401408..+4)            u32    ticket counter (outputs finalize)
//   [401424..+1572864)      u16    eG planes in LDS-order [nt*8+kt][p][q][128][8]
#define WS_TNORM 8
#define WS_SNORM 8192
#define WS_KEYS  139264
#define WS_CNT   401408
#define WS_EG    401424

typedef unsigned long long u64;
typedef unsigned int u32;
typedef unsigned short u16;

typedef __bf16 bf16x8 __attribute__((ext_vector_type(8)));
typedef float f32x16 __attribute__((ext_vector_type(16)));
typedef u16 u16x8 __attribute__((ext_vector_type(8)));

#define LGKM0() asm volatile("s_waitcnt lgkmcnt(0)" ::: "memory")

// ---- numpy pairwise_sum replica over 128 squared terms, stride between terms ----
__device__ __forceinline__ float pw128_sq(const float* x, int stride) {
  float r[8];
#pragma unroll
  for (int j = 0; j < 8; ++j) {
    float v = x[(size_t)j * stride];
    r[j] = __fmul_rn(v, v);
  }
  for (int i = 8; i < 128; i += 8) {
#pragma unroll
    for (int j = 0; j < 8; ++j) {
      float v = x[(size_t)(i + j) * stride];
      r[j] = __fadd_rn(r[j], __fmul_rn(v, v));
    }
  }
  float s01 = __fadd_rn(r[0], r[1]);
  float s23 = __fadd_rn(r[2], r[3]);
  float s45 = __fadd_rn(r[4], r[5]);
  float s67 = __fadd_rn(r[6], r[7]);
  return __fadd_rn(__fadd_rn(s01, s23), __fadd_rn(s45, s67));
}

// 3-way bf16 split (manual rounding) — prep only.
__device__ __forceinline__ void split3(float x, u16& h, u16& m, u16& l) {
  u32 u = __float_as_uint(x);
  u16 hb = (u16)((u + 0x7fffu + ((u >> 16) & 1u)) >> 16);
  float hf = __uint_as_float((u32)hb << 16);
  float r1 = x - hf;                       // exact
  u32 u1 = __float_as_uint(r1);
  u16 mb = (u16)((u1 + 0x7fffu + ((u1 >> 16) & 1u)) >> 16);
  float mf = __uint_as_float((u32)mb << 16);
  float r2 = r1 - mf;                      // exact
  u32 u2 = __float_as_uint(r2);
  u16 lb = (u16)((u2 + 0x7fffu + ((u2 >> 16) & 1u)) >> 16);
  h = hb; m = mb; l = lb;
}

__device__ __forceinline__ u64 shfl_xor_u64(u64 v, int msk) {
  const u32 lo = __shfl_xor((u32)v, msk, 64);
  const u32 hi = __shfl_xor((u32)(v >> 32), msk, 64);
  return ((u64)hi << 32) | lo;
}

// ---- prep (validated R10): keys=~0, loss=0, cnt=0, snorm (blk 0..127);
//      tnorm + e-split into LDS-order planes eG (blk 128..131) ----
__global__ __launch_bounds__(256) void vq_prep_kernel(
    const float* __restrict__ z, const float* __restrict__ emb,
    float* __restrict__ tnorm, float* __restrict__ snorm,
    u64* __restrict__ keys, double* __restrict__ loss_accum,
    u32* __restrict__ counter, u16* __restrict__ eG) {
  const int gid = blockIdx.x * 256 + threadIdx.x;
  if (gid == 0) *loss_accum = 0.0;
  if (gid == 1) *counter = 0u;
  if (gid < NPIX) {
    keys[gid] = ~0ull;
    const int b = gid >> 10, hw = gid & 1023;
    const float* base = z + (size_t)b * (EMB_DIM * HW) + hw;
    snorm[gid] = __fadd_rn(pw128_sq(base, HW), pw128_sq(base + (size_t)128 * HW, HW));
  } else {
    const int k = gid - NPIX;
    if (k < NUM_EMB) {
      const float* row = emb + (size_t)k * EMB_DIM;
      tnorm[k] = __fadd_rn(pw128_sq(row, 1), pw128_sq(row + 128, 1));
      const int nt = k >> 7, er = k & 127;
      for (int c8 = 0; c8 < 32; ++c8) {
        const int c = c8 * 8, kt = c8 >> 2, qq = c8 & 3;
        u16x8 vh, vm, vl;
#pragma unroll
        for (int j = 0; j < 8; ++j) {
          u16 h_, m_, l_;
          split3(row[c + j], h_, m_, l_);
          vh[j] = h_; vm[j] = m_; vl[j] = l_;
        }
        u16* dst = eG + ((((size_t)(nt * 8 + kt) * 3 + 0) * 4 + qq) * 128 + er) * 8;
        *(u16x8*)(dst)        = vh;
        *(u16x8*)(dst + 4096) = vm;   // p stride = 4*128*8 = 4096 u16
        *(u16x8*)(dst + 8192) = vl;
      }
    }
  }
}

// ---- main: 128 px x 128 codes, 512 thr / 8 waves (each 32px x 64codes),
// dbuf LDS (80B rows, measured conflict-free), 2 phases per kt, barrier-pair
// per phase, setprio around MFMA clusters, depth-2 reg prefetch (counted
// vmcnt across raw barriers — never drained). 32x32x16 MFMA; per-acc product
// order bit-identical to validated R9.  XCD swizzle: h -> (h&7)*256+(h>>3)
__global__ __launch_bounds__(512, 2) void vq_main_kernel(
    const float* __restrict__ z, const u16* __restrict__ eG,
    const float* __restrict__ tnorm, const float* __restrict__ snorm,
    u64* __restrict__ keys) {
  __shared__ __align__(16) u16 zs[2][3][128][40];   // 61440 B
  __shared__ __align__(16) u16 es[2][3][128][40];   // 61440 B

  const int t   = threadIdx.x;
  const int hb  = blockIdx.x;
  const int bid = (hb & 7) * 256 + (hb >> 3);
  const int pt  = bid >> 3;
  const int ntb = bid & 7;
  const int m0  = pt * 128;
  const int n0  = ntb * 128;
  const int b   = m0 >> 10;
  const int hw0 = m0 & 1023;

  const int l    = t & 63;
  const int w    = t >> 6;           // 8 waves
  const int wpx0 = (w >> 1) * 32;    // wave pixel group (4 x 32)
  const int wcb  = (w & 1) * 64;     // wave code half (2 x 64)
  const int cl   = l & 31;
  const int hi   = l >> 5;

  // staging: thread owns row p1 (pixel AND code) and k-octet ko
  const int p1 = t & 127;
  const int q  = t >> 7;             // 0..3
  const int ko = q * 8;
  const float* zgbase = z + (size_t)b * (EMB_DIM * HW) + hw0 + p1;

  float gz[8];
  u16x8 ge[3];

  auto load_z = [&](int kt) {
#pragma unroll
    for (int j = 0; j < 8; ++j)
      gz[j] = zgbase[(size_t)(kt * 32 + ko + j) * HW];
  };
  auto load_e = [&](int kt) {
#pragma unroll
    for (int p = 0; p < 3; ++p)
      ge[p] = *(const u16x8*)(eG +
          ((((size_t)(ntb * 8 + kt) * 3 + p) * 4 + q) * 128 + p1) * 8);
  };
  auto write_z = [&](int buf) {   // bf16-cast split (validated R12) + b128 writes
    u16x8 vh, vm, vl;
#pragma unroll
    for (int j = 0; j < 8; ++j) {
      const float x  = gz[j];
      const float hf = (float)(__bf16)x;     // RNE
      const float r1 = x - hf;               // exact (Sterbenz)
      const float mf = (float)(__bf16)r1;    // RNE
      const float r2 = r1 - mf;              // exact
      vh[j] = (u16)(__float_as_uint(hf) >> 16);
      vm[j] = (u16)(__float_as_uint(mf) >> 16);
      vl[j] = (u16)(__float_as_uint((float)(__bf16)r2) >> 16);
    }
    *(u16x8*)&zs[buf][0][p1][ko] = vh;
    *(u16x8*)&zs[buf][1][p1][ko] = vm;
    *(u16x8*)&zs[buf][2][p1][ko] = vl;
  };
  auto write_e = [&](int buf) {
#pragma unroll
    for (int p = 0; p < 3; ++p)
      *(u16x8*)&es[buf][p][p1][ko] = ge[p];
  };

  f32x16 acc[2];
#pragma unroll
  for (int i = 0; i < 2; ++i)
#pragma unroll
    for (int r = 0; r < 16; ++r) acc[i][r] = 0.0f;

  // prologue: stage kt0 -> buf0; hold kt1 in regs; one aligning barrier
  load_z(0); load_e(0);
  write_z(0); write_e(0);
  load_z(1); load_e(1);
  LGKM0();
  __builtin_amdgcn_s_barrier();

  for (int kt = 0; kt < 8; ++kt) {
    const int cur = kt & 1;
    bf16x8 af[2][3], bf[2][3];
    // ================= phase 0 (nn = 0) =================
#pragma unroll
    for (int ks = 0; ks < 2; ++ks)
#pragma unroll
      for (int p = 0; p < 3; ++p) {
        af[ks][p] = *(const bf16x8*)&zs[cur][p][wpx0 + cl][ks * 16 + hi * 8];
        bf[ks][p] = *(const bf16x8*)&es[cur][p][wcb + cl][ks * 16 + hi * 8];
      }
    if (kt < 7) write_z(cur ^ 1);            // kt+1 z (loaded 2 phases ago)
    LGKM0();
    __builtin_amdgcn_s_barrier();
    __builtin_amdgcn_s_setprio(1);
#pragma unroll
    for (int ks = 0; ks < 2; ++ks) {
#define PROD(PA, PB, NN)                                                      \
      acc[NN] = __builtin_amdgcn_mfma_f32_32x32x16_bf16(af[ks][PA],           \
                                                        bf[ks][PB], acc[NN],  \
                                                        0, 0, 0);
      PROD(0, 0, 0) PROD(0, 1, 0) PROD(1, 0, 0)
      PROD(1, 1, 0) PROD(0, 2, 0) PROD(2, 0, 0)
    }
    __builtin_amdgcn_s_setprio(0);
    __builtin_amdgcn_s_barrier();
    // ================= phase 1 (nn = 1) =================
#pragma unroll
    for (int ks = 0; ks < 2; ++ks)
#pragma unroll
      for (int p = 0; p < 3; ++p)
        bf[ks][p] =
            *(const bf16x8*)&es[cur][p][wcb + 32 + cl][ks * 16 + hi * 8];
    if (kt < 7) {
      write_e(cur ^ 1);                      // kt+1 e
      if (kt < 6) { load_z(kt + 2); load_e(kt + 2); }  // depth-2 prefetch
    }
    LGKM0();
    __builtin_amdgcn_s_barrier();
    __builtin_amdgcn_s_setprio(1);
#pragma unroll
    for (int ks = 0; ks < 2; ++ks) {
      PROD(0, 0, 1) PROD(0, 1, 1) PROD(1, 0, 1)
      PROD(1, 1, 1) PROD(0, 2, 1) PROD(2, 0, 1)
#undef PROD
    }
    __builtin_amdgcn_s_setprio(0);
    __builtin_amdgcn_s_barrier();
  }

  // ---- epilogue: d = fl(fl(s+t) - 2m); argmin via u64 keys ----
  // C layout (validated R6-R12): col = cl (code), row = (reg&3)+8*(reg>>2)+4*hi
  const float tv0 = tnorm[n0 + wcb + cl];
  const float tv1 = tnorm[n0 + wcb + 32 + cl];
  u64 bk[16];
#pragma unroll
  for (int reg = 0; reg < 16; ++reg) {
    const int row = wpx0 + (reg & 3) + 8 * (reg >> 2) + 4 * hi;
    const float s = snorm[m0 + row];
    const float d0 = __fsub_rn(__fadd_rn(s, tv0), 2.0f * acc[0][reg]);
    const float d1 = __fsub_rn(__fadd_rn(s, tv1), 2.0f * acc[1][reg]);
    const u64 k0 = ((u64)__float_as_uint(d0) << 32) | (u32)(n0 + wcb + cl);
    const u64 k1 = ((u64)__float_as_uint(d1) << 32) | (u32)(n0 + wcb + 32 + cl);
    bk[reg] = k0 < k1 ? k0 : k1;
  }
#pragma unroll
  for (int off = 1; off < 32; off <<= 1)
#pragma unroll
    for (int reg = 0; reg < 16; ++reg) {
      const u64 o = shfl_xor_u64(bk[reg], off);
      if (o < bk[reg]) bk[reg] = o;
    }

  u64* part = (u64*)&zs[0][0][0][0];   // [128][2], LDS reuse (all reads done)
  if (cl == 0) {
#pragma unroll
    for (int reg = 0; reg < 16; ++reg) {
      const int row = wpx0 + (reg & 3) + 8 * (reg >> 2) + 4 * hi;
      part[row * 2 + (w & 1)] = bk[reg];
    }
  }
  __syncthreads();
  if (t < 128) {
    const u64 a = part[t * 2], c = part[t * 2 + 1];
    atomicMin(&keys[m0 + t], a < c ? a : c);
  }
}

// ---- outputs: z_q gather + straight-through + loss + idx; last block finalizes ----
__global__ __launch_bounds__(256) void vq_outputs_kernel(
    const float* __restrict__ z, const float* __restrict__ emb,
    const u64* __restrict__ keys, float* __restrict__ out,
    float* __restrict__ out_idx_f, double* __restrict__ loss_accum,
    u32* __restrict__ counter, float* __restrict__ out_loss) {
  const int t  = threadIdx.x;
  const int n0 = blockIdx.x * 64;
  const int m  = t & 63;
  const int c0 = t >> 6;
  const int b  = n0 >> 10;
  const int hw = n0 & 1023;
  const float* zb = z   + (size_t)b * (EMB_DIM * HW) + hw + m;
  float*       ob = out + (size_t)b * (EMB_DIM * HW) + hw + m;
  const int idx = (int)(u32)(keys[n0 + m] & 0xffffffffu);
  const float* er = emb + (size_t)idx * EMB_DIM;
  if (c0 == 0) out_idx_f[n0 + m] = (float)idx;

  double lsum = 0.0;
  for (int c = c0; c < EMB_DIM; c += 4) {
    const float e  = er[c];
    const float zv = zb[(size_t)c * HW];
    const float diff = e - zv;       // fl(z_q - z)
    const float zq   = zv + diff;    // straight-through: fl(z + fl(z_q - z))
    ob[(size_t)c * HW] = zq;
    lsum += (double)diff * (double)diff;
  }

  __shared__ double red[256];
  red[t] = lsum;
  __syncthreads();
  for (int s2 = 128; s2 > 0; s2 >>= 1) {
    if (t < s2) red[t] += red[t + s2];
    __syncthreads();
  }
  if (t == 0) {
    atomicAdd(loss_accum, red[0]);
    __threadfence();
    const u32 tick = atomicAdd(counter, 1u);
    if (tick == (u32)(NPIX / 64 - 1)) {
      const double total = atomicAdd(loss_accum, 0.0);  // device-scope read
      const float L = (float)(total / (double)ZQ_ELEMS);
      out_loss[0] = __fadd_rn(L, __fmul_rn(0.25f, L));
    }
  }
}

extern "C" void kernel_launch(void* const* d_in, const int* in_sizes, int n_in,
                              void* d_out, int out_size, void* d_ws, size_t ws_size,
                              hipStream_t stream) {
  const float* z   = (const float*)d_in[0];   // (32, 256, 32, 32) f32
  const float* emb = (const float*)d_in[1];   // (1024, 256) f32

  float* out       = (float*)d_out;           // z_q_out (B,C,H,W)
  float* out_loss  = out + ZQ_ELEMS;          // vq_loss scalar
  float* out_idx_f = out + ZQ_ELEMS + 1;      // encoding_indices as f32

  double* loss_accum = (double*)d_ws;
  float*  tnorm = (float*)((char*)d_ws + WS_TNORM);
  float*  snorm = (float*)((char*)d_ws + WS_SNORM);
  u64*    keys  = (u64*)((char*)d_ws + WS_KEYS);
  u32*    counter = (u32*)((char*)d_ws + WS_CNT);
  u16*    eG    = (u16*)((char*)d_ws + WS_EG);

  vq_prep_kernel<<<132, 256, 0, stream>>>(z, emb, tnorm, snorm, keys, loss_accum,
                                          counter, eG);
  vq_main_kernel<<<2048, 512, 0, stream>>>(z, eG, tnorm, snorm, keys);
  vq_outputs_kernel<<<NPIX / 64, 256, 0, stream>>>(z, emb, keys, out, out_idx_f,
                                                   loss_accum, counter, out_loss);
}